// Round 9
// baseline (220.853 us; speedup 1.0000x reference)
//
#include <hip/hip_runtime.h>
#include <math.h>

#define HD   64
#define EIN  8
#define SAS  168          // !HB: full bf16 W1 row stride in u16
#define W2S  72           // !HB: sW2/X1 row stride in u16 (144 B)
#define X1BS 72           // HB: X1 fp8 row stride in BYTES (16 banks, conflict-free)
#define NORM_INV 0.01f
#define NTH  256
#define NBLK 1536         // r14: 6 blocks/CU x 256 CUs (LDS 18688 -> 8 fit; VGPR caps 6)
#define NWAVES (NBLK * (NTH / 64))

typedef short bf16x8 __attribute__((ext_vector_type(8)));
typedef float f32x4  __attribute__((ext_vector_type(4)));
typedef float f4v    __attribute__((ext_vector_type(4)));

__device__ __forceinline__ unsigned short f2bf(float f) {
    union { float f; unsigned u; } v; v.f = f;
    unsigned r = v.u + 0x7FFFu + ((v.u >> 16) & 1u);
    return (unsigned short)(r >> 16);
}
__device__ __forceinline__ unsigned pk2(float a, float b) {
    return (unsigned)f2bf(a) | ((unsigned)f2bf(b) << 16);
}
// single-instruction packed f32->2xbf16 (RNE)
__device__ __forceinline__ unsigned cvt_pk_bf16(float lo, float hi) {
    unsigned r;
    asm("v_cvt_pk_bf16_f32 %0, %1, %2" : "=v"(r) : "v"(lo), "v"(hi));
    return r;
}
__device__ __forceinline__ float silu_f(float x) {
    return x * __builtin_amdgcn_rcpf(1.0f + __expf(-x));
}
// pair-silu: ONE rcp for two values (r = 1/(ab); 1/a = b*r; 1/b = a*r).
// Saves a 1/4-rate trans op per pair; exact up to one extra rounding.
__device__ __forceinline__ void silu2(float x, float y, float& sx, float& sy) {
    float a = 1.0f + __expf(-x);
    float b = 1.0f + __expf(-y);
    float r = __builtin_amdgcn_rcpf(a * b);
    sx = x * (b * r);
    sy = y * (a * r);
}
__device__ __forceinline__ bf16x8 pack_f8(f4v a, f4v b) {
    union { bf16x8 v; uint4 u; } pk;
    pk.u.x = pk2(a.x, a.y); pk.u.y = pk2(a.z, a.w);
    pk.u.z = pk2(b.x, b.y); pk.u.w = pk2(b.z, b.w);
    return pk.v;
}

// prep: h -> fp8 e4m3 table in ws (3.2 MB -> fits 4 MB/XCD L2) + coord -> out copy
__global__ void prep_h_kernel(const float* __restrict__ h, unsigned char* __restrict__ hf8,
                              int nq, const float* __restrict__ coord,
                              float* __restrict__ out, int n3) {
    int i = blockIdx.x * blockDim.x + threadIdx.x;
    if (i < nq) {
        f4v v = reinterpret_cast<const f4v*>(h)[i];
        int p = __builtin_amdgcn_cvt_pk_fp8_f32(v.x, v.y, 0, false);
        p     = __builtin_amdgcn_cvt_pk_fp8_f32(v.z, v.w, p, true);
        reinterpret_cast<int*>(hf8)[i] = p;
    }
    if (i < n3) out[i] = coord[i];
}

__global__ void prep_out_kernel(const float* __restrict__ coord,
                                float* __restrict__ out, int n3) {
    int i = blockIdx.x * blockDim.x + threadIdx.x;
    if (i < n3) out[i] = coord[i];
}

// r14 ledger:
//  r13: 122 -> 118 us; occ 38 -> 47 but slope collapsed (+23% occ, -3.5% dur)
//    -> VALU-pipe wall. Arithmetic: 66 trans/iter x 16cyc (1/4-rate wave64)
//    = ~1050 of ~1550 VALU cycles/iter = silu exp+rcp. VALUBusy 57%.
//  r14: (a) pair-rcp silu (32 -> 17 rcp/iter, exact algebra);
//    (b) fp8 layer-2: W2 pre-scaled x8 -> e4m3 frags (9216 -> 4096 B),
//        X1 stored fp8 (9216 -> 4608 B, 72-B rows = conflict-free reads);
//        LDS 28416 -> 18688 -> 6 blocks/CU (VGPR 76incl-acc -> 6 waves/SIMD).
//        launch_bounds stays (,5): residency is resource-set (r9 lesson);
//        grid 1536 = 6 exact.
//  Keystones: LDS ~18688; occ 60-70; VGPR ~44; FETCH ~70 MB; absmax ~0.03
//    (if fail: revert fp8-X1 only, keep pair-rcp).
template <bool HB>
__global__ __launch_bounds__(NTH, 5) void egnn_mfma_kernel(
    const float* __restrict__ h,             // fp32 h (when !HB)
    const unsigned char* __restrict__ hf8,   // fp8 h table in ws (when HB)
    const float* __restrict__ coord,
    const int*   __restrict__ eidx,   // [2][E]
    const float* __restrict__ eattr,  // [E][8]
    const float* __restrict__ W1f,    // [136][64] fp32 (k-major)
    const float* __restrict__ W2f,    // [64][64] fp32 (k-major)
    const float* __restrict__ b1,
    const float* __restrict__ b2,
    const float* __restrict__ W3,
    float* __restrict__ out,
    int E_)
{
    // HB layout:  [0,8192) fp8 W1 frags | [8192,9216) bf16 W1 tail |
    //             [9216,13312) fp8 W2 frags | [13312,17920) fp8 X1 (64x72B) |
    //             [17920,18688) biases
    // !HB layout: [0,21504) bf16 W1 | [21504,30720) sW2 | [30720,39936) sX1 | ...
    constexpr int LDS_BYTES = HB ? 18688 : 40704;
    __shared__ __align__(16) char lds[LDS_BYTES];

    unsigned long*  sW1f8 = (unsigned long*)lds;                         // HB
    unsigned short* sW1b  = (unsigned short*)(lds + 8192);               // HB
    unsigned long*  sW2f8 = (unsigned long*)(lds + 9216);                // HB
    unsigned char*  sX1b  = (unsigned char*)(lds + 13312);               // HB
    unsigned short* sW1   = (unsigned short*)lds;                        // !HB
    unsigned short* sW2   = (unsigned short*)(lds + 21504);              // !HB
    unsigned short* sX1   = (unsigned short*)(lds + 30720);              // !HB
    float*          sB1   = (float*)(lds + (HB ? 17920 : 39936));
    float*          sB2   = sB1 + 64;
    float*          sW3   = sB1 + 128;

    const int t = threadIdx.x;

    // ---- weights -> LDS (once per block) ----
    if (HB) {
        // fp8 W1 fragments, per (nt,s,lane): lane holds
        // W1s[n2=16nt+m][k = s*32 + q*8 .. +7], W1 scaled x8 into e4m3 range.
        for (int f = t; f < 16 * 64; f += NTH) {
            int frag = f >> 6, ln = f & 63;
            int nt = frag >> 2, s = frag & 3;
            int mm = ln & 15, qq = ln >> 4;
            int n2 = nt * 16 + mm, kb = s * 32 + qq * 8;
            unsigned long v = 0;
#pragma unroll
            for (int j = 0; j < 8; j += 2) {
                float a = W1f[(kb + j) * 64 + n2] * 8.0f;
                float b = W1f[(kb + j + 1) * 64 + n2] * 8.0f;
                int p = __builtin_amdgcn_cvt_pk_fp8_f32(a, b, 0, false);
                v |= ((unsigned long)(unsigned)(p & 0xFFFF)) << (j * 8);
            }
            sW1f8[f] = v;
        }
        // bf16 W1 tail: ONLY the 8 real k (128..135), row-major [n2][8].
        for (int i = t; i < 64 * 8; i += NTH) {
            int n2 = i >> 3, kk = i & 7;
            sW1b[i] = f2bf(W1f[(128 + kk) * 64 + n2]);
        }
        // fp8 W2 fragments, per (nt,s in 0..1, lane): W2s[n2][k=s*32+q*8..+7] x8
        for (int f = t; f < 8 * 64; f += NTH) {
            int frag = f >> 6, ln = f & 63;
            int nt = frag >> 1, s = frag & 1;
            int mm = ln & 15, qq = ln >> 4;
            int n2 = nt * 16 + mm, kb = s * 32 + qq * 8;
            unsigned long v = 0;
#pragma unroll
            for (int j = 0; j < 8; j += 2) {
                float a = W2f[(kb + j) * 64 + n2] * 8.0f;
                float b = W2f[(kb + j + 1) * 64 + n2] * 8.0f;
                int p = __builtin_amdgcn_cvt_pk_fp8_f32(a, b, 0, false);
                v |= ((unsigned long)(unsigned)(p & 0xFFFF)) << (j * 8);
            }
            sW2f8[f] = v;
        }
    } else {
        for (int i = t; i < 136 * 64; i += NTH) {
            int k = i >> 6, n = i & 63;
            sW1[n * SAS + k] = f2bf(W1f[i]);
        }
        for (int i = t; i < 24 * 64; i += NTH) {
            int n = i / 24, k = 136 + (i - n * 24);
            sW1[n * SAS + k] = 0;
        }
        for (int i = t; i < 64 * 64; i += NTH) {
            int k = i >> 6, n = i & 63;
            sW2[n * W2S + k] = f2bf(W2f[i]);
        }
    }
    if (t < 64) sB1[t] = b1[t];
    else if (t < 128) sB2[t - 64] = b2[t - 64];
    else if (t < 192) sW3[t - 128] = W3[t - 128];
    __syncthreads();                               // the ONLY barrier

    const int w = t >> 6, lane = t & 63;
    const int m = lane & 15, q = lane >> 4;

    unsigned char*  x1RowB = sX1b + (16 * w + m) * X1BS;          // HB
    unsigned short* x1Row  = sX1 + (16 * w + m) * W2S;            // !HB

    const int ngroups = (E_ + 15) >> 4;
    for (int g = blockIdx.x * (NTH / 64) + w; g < ngroups; g += NWAVES) {
        int e = g * 16 + m;
        int ec = (e < E_) ? e : (E_ - 1);
        int row = __builtin_nontemporal_load(eidx + ec);
        int col = __builtin_nontemporal_load(eidx + (size_t)E_ + ec);

        // coord loads issued early (L2-resident table)
        float cr = 0.f, cc = 0.f;
        if (q < 3) { cr = coord[row * 3 + q]; cc = coord[col * 3 + q]; }

        // ---------- eattr fragment (bf16, k=128..135 on q==0) ----------
        bf16x8 bf4;
        {
            union { bf16x8 v; uint4 u; } pk;
            pk.u.x = 0; pk.u.y = 0; pk.u.z = 0; pk.u.w = 0;
            if (q == 0) {
                const f4v* ea = (const f4v*)(eattr + (size_t)ec * EIN);
                f4v a0 = __builtin_nontemporal_load(ea);
                f4v a1 = __builtin_nontemporal_load(ea + 1);
                pk.u.x = cvt_pk_bf16(a0.x, a0.y);
                pk.u.y = cvt_pk_bf16(a0.z, a0.w);
                pk.u.z = cvt_pk_bf16(a1.x, a1.y);
                pk.u.w = cvt_pk_bf16(a1.z, a1.w);
            }
            bf4 = pk.v;
        }

        f32x4 acc1[4] = {};

        if (HB) {
            // ---------- layer-1 h-part: fp8 gathers (8 B each, L2-resident) ----------
            const unsigned long* hr8 = (const unsigned long*)(hf8 + (size_t)row * HD);
            const unsigned long* hc8 = (const unsigned long*)(hf8 + (size_t)col * HD);
            long b0 = (long)hr8[q];         // k =      q*8
            long b1v = (long)hr8[4 + q];    // k = 32 + q*8
            long b2v = (long)hc8[q];        // k = 64 + ...
            long b3v = (long)hc8[4 + q];    // k = 96 + ...
            __builtin_amdgcn_s_setprio(1);
#define L1F8(S, B)                                                            \
            _Pragma("unroll")                                                 \
            for (int nt = 0; nt < 4; ++nt) {                                  \
                long a8 = (long)sW1f8[((nt << 2) | (S)) * 64 + lane];         \
                acc1[nt] = __builtin_amdgcn_mfma_f32_16x16x32_fp8_fp8(a8, B, acc1[nt], 0, 0, 0); \
            }
            L1F8(0, b0)
            L1F8(1, b1v)
            L1F8(2, b2v)
            L1F8(3, b3v)
#undef L1F8
            // eattr tail (bf16 MFMA): broadcast-read, q>=1 slices killed by zeros.
#pragma unroll
            for (int nt = 0; nt < 4; ++nt) {
                bf16x8 afb = *(const bf16x8*)(sW1b + (16 * nt + m) * 8);
                acc1[nt] = __builtin_amdgcn_mfma_f32_16x16x32_bf16(afb, bf4, acc1[nt], 0, 0, 0);
            }
            __builtin_amdgcn_s_setprio(0);
        } else {
            bf16x8 bf[5];
            const f4v* hr = (const f4v*)(h + (size_t)row * HD);
            const f4v* hc = (const f4v*)(h + (size_t)col * HD);
#pragma unroll
            for (int s = 0; s < 4; ++s) {
                const f4v* src = (s < 2) ? hr : hc;
                f4v a = src[(s & 1) * 8 + q * 2];
                f4v b = src[(s & 1) * 8 + q * 2 + 1];
                bf[s] = pack_f8(a, b);
            }
            bf[4] = bf4;
#pragma unroll
            for (int s = 0; s < 5; ++s) {
#pragma unroll
                for (int nt = 0; nt < 4; ++nt) {
                    bf16x8 afrag = *(const bf16x8*)(sW1 + (16 * nt + m) * SAS + s * 32 + q * 8);
                    acc1[nt] = __builtin_amdgcn_mfma_f32_16x16x32_bf16(afrag, bf[s], acc1[nt], 0, 0, 0);
                }
            }
        }

        // silu(fmaf(acc1, sc, b1)) -> X1; sc folds the fp8 x8 pre-scale
        const float sc = HB ? 0.125f : 1.0f;
#pragma unroll
        for (int nt = 0; nt < 4; ++nt) {
            float4 bb = *(const float4*)(&sB1[16 * nt + 4 * q]);
            float s0, s1, s2, s3;
            silu2(fmaf(acc1[nt][0], sc, bb.x), fmaf(acc1[nt][1], sc, bb.y), s0, s1);
            silu2(fmaf(acc1[nt][2], sc, bb.z), fmaf(acc1[nt][3], sc, bb.w), s2, s3);
            if (HB) {
                int p = __builtin_amdgcn_cvt_pk_fp8_f32(s0, s1, 0, false);
                p     = __builtin_amdgcn_cvt_pk_fp8_f32(s2, s3, p, true);
                *((unsigned*)(x1RowB + 16 * nt + 4 * q)) = (unsigned)p;
            } else {
                uint2 o;
                o.x = cvt_pk_bf16(s0, s1);
                o.y = cvt_pk_bf16(s2, s3);
                *((uint2*)(x1Row + 16 * nt + 4 * q)) = o;
            }
        }

        // ---------- layer 2 ----------
        f32x4 acc2[4] = {};
        __builtin_amdgcn_s_setprio(1);
        if (HB) {
#pragma unroll
            for (int s = 0; s < 2; ++s) {
                long bfrag = *(const long*)(x1RowB + s * 32 + q * 8);
#pragma unroll
                for (int nt = 0; nt < 4; ++nt) {
                    long a8 = (long)sW2f8[((nt << 1) | s) * 64 + lane];
                    acc2[nt] = __builtin_amdgcn_mfma_f32_16x16x32_fp8_fp8(a8, bfrag, acc2[nt], 0, 0, 0);
                }
            }
        } else {
#pragma unroll
            for (int s = 0; s < 2; ++s) {
                bf16x8 bfrag = *(const bf16x8*)(x1Row + s * 32 + q * 8);
#pragma unroll
                for (int nt = 0; nt < 4; ++nt) {
                    bf16x8 afrag = *(const bf16x8*)(sW2 + (16 * nt + m) * W2S + s * 32 + q * 8);
                    acc2[nt] = __builtin_amdgcn_mfma_f32_16x16x32_bf16(afrag, bfrag, acc2[nt], 0, 0, 0);
                }
            }
        }
        __builtin_amdgcn_s_setprio(0);

        // ---------- epilogue: scal = silu(X2) . W3 (pair-rcp silu) ----------
        const float sc2 = HB ? 0.125f : 1.0f;
        float p = 0.f;
#pragma unroll
        for (int nt = 0; nt < 4; ++nt) {
            float4 b2v2 = *(const float4*)(&sB2[16 * nt + 4 * q]);
            float4 w3v  = *(const float4*)(&sW3[16 * nt + 4 * q]);
            float s0, s1, s2, s3;
            silu2(fmaf(acc2[nt][0], sc2, b2v2.x), fmaf(acc2[nt][1], sc2, b2v2.y), s0, s1);
            silu2(fmaf(acc2[nt][2], sc2, b2v2.z), fmaf(acc2[nt][3], sc2, b2v2.w), s2, s3);
            p = fmaf(s0, w3v.x, p);
            p = fmaf(s1, w3v.y, p);
            p = fmaf(s2, w3v.z, p);
            p = fmaf(s3, w3v.w, p);
        }
        p += __shfl_xor(p, 16);
        p += __shfl_xor(p, 32);

        float cd = cr - cc;
        float r2 = cd * cd;
        r2 += __shfl_xor(r2, 16);
        r2 += __shfl_xor(r2, 32);
        if (e < E_ && q < 3) {
            float inv = __builtin_amdgcn_rcpf(sqrtf(r2 + 1e-8f) + 1.0f);
            atomicAdd(&out[row * 3 + q], cd * (p * NORM_INV * inv));
        }
    }
}

extern "C" void kernel_launch(void* const* d_in, const int* in_sizes, int n_in,
                              void* d_out, int out_size, void* d_ws, size_t ws_size,
                              hipStream_t stream) {
    const float* h         = (const float*)d_in[0];
    const float* coord     = (const float*)d_in[1];
    const int*   eidx      = (const int*)  d_in[2];
    const float* edge_attr = (const float*)d_in[3];
    const float* W1        = (const float*)d_in[4];
    const float* b1        = (const float*)d_in[5];
    const float* W2        = (const float*)d_in[6];
    const float* b2        = (const float*)d_in[7];
    const float* W3        = (const float*)d_in[8];
    float* out = (float*)d_out;

    int E_ = in_sizes[2] / 2;    // edge_index is [2, E]
    int n3 = out_size;           // N*3
    int nf = in_sizes[0];        // N*HD floats of h

    if (ws_size >= (size_t)nf) {                 // fp8 h table (3.2 MB)
        unsigned char* hf8 = (unsigned char*)d_ws;
        int nq = nf / 4;
        int pgrid = (nq > n3 ? nq : n3);
        hipLaunchKernelGGL(prep_h_kernel, dim3((pgrid + 255) / 256), dim3(256), 0, stream,
                           h, hf8, nq, coord, out, n3);
        hipLaunchKernelGGL((egnn_mfma_kernel<true>), dim3(NBLK), dim3(NTH), 0, stream,
                           h, hf8, coord, eidx, edge_attr, W1, W2, b1, b2, W3, out, E_);
    } else {
        hipLaunchKernelGGL(prep_out_kernel, dim3((n3 + 255) / 256), dim3(256), 0, stream,
                           coord, out, n3);
        hipLaunchKernelGGL((egnn_mfma_kernel<false>), dim3(NBLK), dim3(NTH), 0, stream,
                           h, (const unsigned char*)nullptr, coord, eidx, edge_attr,
                           W1, W2, b1, b2, W3, out, E_);
    }
}